// Round 1
// baseline (1439.147 us; speedup 1.0000x reference)
//
#include <hip/hip_runtime.h>
#include <math.h>

#define NN 100000
#define DI 64
#define DH 128
#define DO 40

__global__ void count_kernel(const int* __restrict__ dst, int* __restrict__ cnt, int E) {
    int e = blockIdx.x * 256 + threadIdx.x;
    if (e < E) atomicAdd(&cnt[dst[e]], 1);
}

__global__ void inv_kernel(const int* __restrict__ cnt, float* __restrict__ inv, int N) {
    int n = blockIdx.x * 256 + threadIdx.x;
    if (n < N) { int c = cnt[n]; inv[n] = 1.0f / (float)(c > 0 ? c : 1); }
}

// dst[c*rows + r] = src[r*cols + c]
__global__ void transpose_kernel(float* __restrict__ dstp, const float* __restrict__ srcp,
                                 int rows, int cols) {
    int i = blockIdx.x * 256 + threadIdx.x;
    if (i < rows * cols) {
        int r = i / cols, c = i - r * cols;
        dstp[c * rows + r] = srcp[i];
    }
}

// wave (64 lanes) per edge, 64 dims
__global__ void scatter1_kernel(const int* __restrict__ src, const int* __restrict__ dst,
                                const float* __restrict__ x, float* __restrict__ agg, int E) {
    int e = blockIdx.x * 4 + (threadIdx.x >> 6);
    int lane = threadIdx.x & 63;
    if (e < E) {
        int s = src[e], d = dst[e];
        atomicAdd(&agg[(size_t)d * DI + lane], x[(size_t)s * DI + lane]);
    }
}

// 128 threads per edge, 128 dims
__global__ void scatter2_kernel(const int* __restrict__ src, const int* __restrict__ dst,
                                const float* __restrict__ h, float* __restrict__ agg, int E) {
    int e = blockIdx.x * 2 + (threadIdx.x >> 7);
    int c = threadIdx.x & 127;
    if (e < E) {
        int s = src[e], d = dst[e];
        atomicAdd(&agg[(size_t)d * DH + c], h[(size_t)s * DH + c]);
    }
}

// h[n] = relu( (agg1[n]*inv[n]) @ W1l^T + b1 + x[n] @ W1r^T )
// 16 nodes per block of 256 threads; thread = (half, j); 8 node-accumulators each
__global__ __launch_bounds__(256) void layer1_kernel(
        const float* __restrict__ x, const float* __restrict__ agg,
        const float* __restrict__ inv, const float* __restrict__ W1lT,
        const float* __restrict__ W1rT, const float* __restrict__ b1,
        float* __restrict__ h, int N) {
    __shared__ float xs[16][DI];
    __shared__ float as[16][DI];
    int n0 = blockIdx.x * 16;
    int tid = threadIdx.x;
    for (int i = tid; i < 16 * DI; i += 256) {
        int t = i >> 6, k = i & 63;
        int n = n0 + t;
        float xv = 0.f, av = 0.f;
        if (n < N) {
            xv = x[(size_t)n * DI + k];
            av = agg[(size_t)n * DI + k] * inv[n];
        }
        xs[t][k] = xv; as[t][k] = av;
    }
    __syncthreads();
    int j = tid & 127, half = tid >> 7;
    float bj = b1[j];
    float acc[8];
#pragma unroll
    for (int t = 0; t < 8; t++) acc[t] = bj;
    for (int k = 0; k < DI; k++) {
        float wl = W1lT[k * DH + j];
        float wr = W1rT[k * DH + j];
#pragma unroll
        for (int t = 0; t < 8; t++)
            acc[t] += as[half * 8 + t][k] * wl + xs[half * 8 + t][k] * wr;
    }
#pragma unroll
    for (int t = 0; t < 8; t++) {
        int n = n0 + half * 8 + t;
        if (n < N) h[(size_t)n * DH + j] = fmaxf(acc[t], 0.f);
    }
}

// out[n] = log_softmax( (agg2[n]*inv[n]) @ W2l^T + b2 + h[n] @ W2r^T )
// 16 nodes per 256-thread block; each wave handles 4 nodes; lanes 0..39 = outputs
__global__ __launch_bounds__(256) void layer2_kernel(
        const float* __restrict__ h, const float* __restrict__ agg,
        const float* __restrict__ inv, const float* __restrict__ W2lT,
        const float* __restrict__ W2rT, const float* __restrict__ b2,
        float* __restrict__ out, int N) {
    __shared__ float hs[16][DH];
    __shared__ float gs[16][DH];
    int n0 = blockIdx.x * 16;
    int tid = threadIdx.x;
    for (int i = tid; i < 16 * DH; i += 256) {
        int t = i >> 7, k = i & 127;
        int n = n0 + t;
        float hv = 0.f, gv = 0.f;
        if (n < N) {
            hv = h[(size_t)n * DH + k];
            gv = agg[(size_t)n * DH + k] * inv[n];
        }
        hs[t][k] = hv; gs[t][k] = gv;
    }
    __syncthreads();
    int wave = tid >> 6, lane = tid & 63;
    int j = lane;
    float bj = (j < DO) ? b2[j] : 0.f;
    float acc[4];
#pragma unroll
    for (int t = 0; t < 4; t++) acc[t] = bj;
    if (j < DO) {
        for (int k = 0; k < DH; k++) {
            float wl = W2lT[k * DO + j];
            float wr = W2rT[k * DO + j];
#pragma unroll
            for (int t = 0; t < 4; t++) {
                int tt = wave * 4 + t;
                acc[t] += gs[tt][k] * wl + hs[tt][k] * wr;
            }
        }
    }
#pragma unroll
    for (int t = 0; t < 4; t++) {
        int n = n0 + wave * 4 + t;
        float v = (j < DO) ? acc[t] : -INFINITY;
        float m = v;
#pragma unroll
        for (int off = 32; off >= 1; off >>= 1) m = fmaxf(m, __shfl_xor(m, off, 64));
        float ex = (j < DO) ? expf(acc[t] - m) : 0.f;
        float s = ex;
#pragma unroll
        for (int off = 32; off >= 1; off >>= 1) s += __shfl_xor(s, off, 64);
        if (n < N && j < DO) out[(size_t)n * DO + j] = acc[t] - m - logf(s);
    }
}

extern "C" void kernel_launch(void* const* d_in, const int* in_sizes, int n_in,
                              void* d_out, int out_size, void* d_ws, size_t ws_size,
                              hipStream_t stream) {
    const float* x   = (const float*)d_in[0];
    const int*  ei   = (const int*)d_in[1];
    const float* W1l = (const float*)d_in[2];
    const float* b1  = (const float*)d_in[3];
    const float* W1r = (const float*)d_in[4];
    const float* W2l = (const float*)d_in[5];
    const float* b2  = (const float*)d_in[6];
    const float* W2r = (const float*)d_in[7];
    float* out = (float*)d_out;

    const int E = in_sizes[1] / 2;
    const int N = NN;
    const int* src = ei;
    const int* dst = ei + E;

    // workspace layout (floats), 64-float aligned chunks.
    // zeroed region first: cnt, agg1, agg2
    size_t off = 0;
    auto alloc = [&](size_t nf) { size_t o = off; off += (nf + 63) & ~(size_t)63; return o; };
    size_t o_cnt  = alloc(N);            // int
    size_t o_agg1 = alloc((size_t)N * DI);
    size_t o_agg2 = alloc((size_t)N * DH);
    size_t zero_floats = off;
    size_t o_inv  = alloc(N);
    size_t o_h    = alloc((size_t)N * DH);
    size_t o_w1lt = alloc(DI * DH);
    size_t o_w1rt = alloc(DI * DH);
    size_t o_w2lt = alloc(DH * DO);
    size_t o_w2rt = alloc(DH * DO);

    float* ws = (float*)d_ws;
    int*   cnt  = (int*)(ws + o_cnt);
    float* agg1 = ws + o_agg1;
    float* agg2 = ws + o_agg2;
    float* inv  = ws + o_inv;
    float* h    = ws + o_h;
    float* W1lT = ws + o_w1lt;
    float* W1rT = ws + o_w1rt;
    float* W2lT = ws + o_w2lt;
    float* W2rT = ws + o_w2rt;

    hipMemsetAsync(d_ws, 0, zero_floats * sizeof(float), stream);

    // weight transposes
    transpose_kernel<<<(DH * DI + 255) / 256, 256, 0, stream>>>(W1lT, W1l, DH, DI);
    transpose_kernel<<<(DH * DI + 255) / 256, 256, 0, stream>>>(W1rT, W1r, DH, DI);
    transpose_kernel<<<(DO * DH + 255) / 256, 256, 0, stream>>>(W2lT, W2l, DO, DH);
    transpose_kernel<<<(DO * DH + 255) / 256, 256, 0, stream>>>(W2rT, W2r, DO, DH);

    count_kernel<<<(E + 255) / 256, 256, 0, stream>>>(dst, cnt, E);
    inv_kernel<<<(N + 255) / 256, 256, 0, stream>>>(cnt, inv, N);

    scatter1_kernel<<<(E + 3) / 4, 256, 0, stream>>>(src, dst, x, agg1, E);
    layer1_kernel<<<(N + 15) / 16, 256, 0, stream>>>(x, agg1, inv, W1lT, W1rT, b1, h, N);
    scatter2_kernel<<<(E + 1) / 2, 256, 0, stream>>>(src, dst, h, agg2, E);
    layer2_kernel<<<(N + 15) / 16, 256, 0, stream>>>(h, agg2, inv, W2lT, W2rT, b2, out, N);
}

// Round 2
// 868.487 us; speedup vs baseline: 1.6571x; 1.6571x over previous
//
#include <hip/hip_runtime.h>
#include <math.h>

#define NN 100000
#define DI 64
#define DH 128
#define DO 40

// ---------- CSR build ----------

__global__ void count_kernel(const int* __restrict__ dst, int* __restrict__ cnt, int E) {
    int e = blockIdx.x * 256 + threadIdx.x;
    if (e < E) atomicAdd(&cnt[dst[e]], 1);
}

// one block, 1024 threads: exclusive scan of cnt -> rowptr (and cursor copy)
__global__ __launch_bounds__(1024) void scan_kernel(const int* __restrict__ cnt,
                                                    int* __restrict__ rowptr,
                                                    int* __restrict__ cursor, int N) {
    __shared__ int sums[1024];
    int t = threadIdx.x;
    int chunk = (N + 1023) >> 10;
    int lo = t * chunk;
    int hi = lo + chunk; if (hi > N) hi = N;
    int s = 0;
    for (int i = lo; i < hi; i++) s += cnt[i];
    sums[t] = s;
    __syncthreads();
    for (int off = 1; off < 1024; off <<= 1) {
        int v = (t >= off) ? sums[t - off] : 0;
        __syncthreads();
        sums[t] += v;
        __syncthreads();
    }
    int prefix = (t == 0) ? 0 : sums[t - 1];
    for (int i = lo; i < hi; i++) {
        rowptr[i] = prefix;
        cursor[i] = prefix;
        prefix += cnt[i];
    }
}

__global__ void fill_kernel(const int* __restrict__ src, const int* __restrict__ dst,
                            int* __restrict__ cursor, int* __restrict__ col, int E) {
    int e = blockIdx.x * 256 + threadIdx.x;
    if (e < E) {
        int pos = atomicAdd(&cursor[dst[e]], 1);
        col[pos] = src[e];
    }
}

__global__ void inv_kernel(const int* __restrict__ cnt, float* __restrict__ inv, int N) {
    int n = blockIdx.x * 256 + threadIdx.x;
    if (n < N) { int c = cnt[n]; inv[n] = 1.0f / (float)(c > 0 ? c : 1); }
}

// dst[c*rows + r] = src[r*cols + c]
__global__ void transpose_kernel(float* __restrict__ dstp, const float* __restrict__ srcp,
                                 int rows, int cols) {
    int i = blockIdx.x * 256 + threadIdx.x;
    if (i < rows * cols) {
        int r = i / cols, c = i - r * cols;
        dstp[c * rows + r] = srcp[i];
    }
}

// ---------- layer 1 ----------

// wave per node: agg1[n][lane] = inv[n] * sum_{i in row} x[col[i]][lane]
__global__ void agg1_kernel(const float* __restrict__ x, const int* __restrict__ rowptr,
                            const int* __restrict__ cnt, const float* __restrict__ inv,
                            const int* __restrict__ col, float* __restrict__ agg, int N) {
    int n = (blockIdx.x * 256 + threadIdx.x) >> 6;
    int lane = threadIdx.x & 63;
    if (n >= N) return;
    int beg = rowptr[n], deg = cnt[n];
    float acc = 0.f;
    int i = 0;
    for (; i + 4 <= deg; i += 4) {
        int s0 = col[beg + i], s1 = col[beg + i + 1];
        int s2 = col[beg + i + 2], s3 = col[beg + i + 3];
        float a = x[(size_t)s0 * DI + lane];
        float b = x[(size_t)s1 * DI + lane];
        float c = x[(size_t)s2 * DI + lane];
        float d = x[(size_t)s3 * DI + lane];
        acc += (a + b) + (c + d);
    }
    for (; i < deg; i++) acc += x[(size_t)col[beg + i] * DI + lane];
    agg[(size_t)n * DI + lane] = acc * inv[n];
}

// h[n] = relu( agg1[n] @ W1l^T + b1 + x[n] @ W1r^T )
__global__ __launch_bounds__(256) void layer1_kernel(
        const float* __restrict__ x, const float* __restrict__ agg,
        const float* __restrict__ W1lT, const float* __restrict__ W1rT,
        const float* __restrict__ b1, float* __restrict__ h, int N) {
    __shared__ float xs[16][DI];
    __shared__ float as[16][DI];
    int n0 = blockIdx.x * 16;
    int tid = threadIdx.x;
    for (int i = tid; i < 16 * DI; i += 256) {
        int t = i >> 6, k = i & 63;
        int n = n0 + t;
        float xv = 0.f, av = 0.f;
        if (n < N) {
            xv = x[(size_t)n * DI + k];
            av = agg[(size_t)n * DI + k];
        }
        xs[t][k] = xv; as[t][k] = av;
    }
    __syncthreads();
    int j = tid & 127, half = tid >> 7;
    float bj = b1[j];
    float acc[8];
#pragma unroll
    for (int t = 0; t < 8; t++) acc[t] = bj;
    for (int k = 0; k < DI; k++) {
        float wl = W1lT[k * DH + j];
        float wr = W1rT[k * DH + j];
#pragma unroll
        for (int t = 0; t < 8; t++)
            acc[t] += as[half * 8 + t][k] * wl + xs[half * 8 + t][k] * wr;
    }
#pragma unroll
    for (int t = 0; t < 8; t++) {
        int n = n0 + half * 8 + t;
        if (n < N) h[(size_t)n * DH + j] = fmaxf(acc[t], 0.f);
    }
}

// ---------- layer 2 (transform-then-aggregate) ----------

// p2lp[n][lane] = (lane<40) ? (W2l @ h[n])[lane] : 0   (padded to 64)
// selfp[n][j]   = (W2r @ h[n])[j] + b2[j]
__global__ __launch_bounds__(256) void precompute2_kernel(
        const float* __restrict__ h, const float* __restrict__ W2lT,
        const float* __restrict__ W2rT, const float* __restrict__ b2,
        float* __restrict__ p2lp, float* __restrict__ selfp, int N) {
    __shared__ float hs[16][DH];
    int n0 = blockIdx.x * 16;
    int tid = threadIdx.x;
    for (int i = tid; i < 16 * DH; i += 256) {
        int t = i >> 7, k = i & 127;
        int n = n0 + t;
        hs[t][k] = (n < N) ? h[(size_t)n * DH + k] : 0.f;
    }
    __syncthreads();
    int wave = tid >> 6, lane = tid & 63;
    float accl[4], accr[4];
    float bj = (lane < DO) ? b2[lane] : 0.f;
#pragma unroll
    for (int t = 0; t < 4; t++) { accl[t] = 0.f; accr[t] = bj; }
    if (lane < DO) {
        for (int k = 0; k < DH; k++) {
            float wl = W2lT[k * DO + lane];
            float wr = W2rT[k * DO + lane];
#pragma unroll
            for (int t = 0; t < 4; t++) {
                float hv = hs[wave * 4 + t][k];
                accl[t] += hv * wl;
                accr[t] += hv * wr;
            }
        }
    }
#pragma unroll
    for (int t = 0; t < 4; t++) {
        int n = n0 + wave * 4 + t;
        if (n < N) {
            p2lp[(size_t)n * 64 + lane] = (lane < DO) ? accl[t] : 0.f;
            if (lane < DO) selfp[(size_t)n * DO + lane] = accr[t];
        }
    }
}

// wave per node: out[n] = log_softmax( inv[n]*sum_{i} p2lp[col[i]] + selfp[n] )
__global__ void agg2_softmax_kernel(const float* __restrict__ p2lp,
                                    const float* __restrict__ selfp,
                                    const int* __restrict__ rowptr,
                                    const int* __restrict__ cnt,
                                    const float* __restrict__ inv,
                                    const int* __restrict__ col,
                                    float* __restrict__ out, int N) {
    int n = (blockIdx.x * 256 + threadIdx.x) >> 6;
    int lane = threadIdx.x & 63;
    if (n >= N) return;
    int beg = rowptr[n], deg = cnt[n];
    float acc = 0.f;
    int i = 0;
    for (; i + 4 <= deg; i += 4) {
        int s0 = col[beg + i], s1 = col[beg + i + 1];
        int s2 = col[beg + i + 2], s3 = col[beg + i + 3];
        float a = p2lp[(size_t)s0 * 64 + lane];
        float b = p2lp[(size_t)s1 * 64 + lane];
        float c = p2lp[(size_t)s2 * 64 + lane];
        float d = p2lp[(size_t)s3 * 64 + lane];
        acc += (a + b) + (c + d);
    }
    for (; i < deg; i++) acc += p2lp[(size_t)col[beg + i] * 64 + lane];
    float v = acc * inv[n];
    if (lane < DO) v += selfp[(size_t)n * DO + lane];
    float val = (lane < DO) ? v : -INFINITY;
    float m = val;
#pragma unroll
    for (int off = 32; off >= 1; off >>= 1) m = fmaxf(m, __shfl_xor(m, off, 64));
    float ex = (lane < DO) ? expf(v - m) : 0.f;
    float s = ex;
#pragma unroll
    for (int off = 32; off >= 1; off >>= 1) s += __shfl_xor(s, off, 64);
    if (lane < DO) out[(size_t)n * DO + lane] = v - m - logf(s);
}

extern "C" void kernel_launch(void* const* d_in, const int* in_sizes, int n_in,
                              void* d_out, int out_size, void* d_ws, size_t ws_size,
                              hipStream_t stream) {
    const float* x   = (const float*)d_in[0];
    const int*  ei   = (const int*)d_in[1];
    const float* W1l = (const float*)d_in[2];
    const float* b1  = (const float*)d_in[3];
    const float* W1r = (const float*)d_in[4];
    const float* W2l = (const float*)d_in[5];
    const float* b2  = (const float*)d_in[6];
    const float* W2r = (const float*)d_in[7];
    float* out = (float*)d_out;

    const int E = in_sizes[1] / 2;
    const int N = NN;
    const int* src = ei;
    const int* dst = ei + E;

    size_t off = 0;
    auto alloc = [&](size_t nf) { size_t o = off; off += (nf + 63) & ~(size_t)63; return o; };
    size_t o_cnt    = alloc(N);            // int, zeroed
    size_t zero_floats = off;
    size_t o_rowptr = alloc(N + 1);        // int
    size_t o_cursor = alloc(N);            // int
    size_t o_col    = alloc(E);            // int
    size_t o_inv    = alloc(N);
    size_t o_agg1   = alloc((size_t)N * DI);
    size_t o_h      = alloc((size_t)N * DH);
    size_t o_p2lp   = alloc((size_t)N * 64);
    size_t o_selfp  = alloc((size_t)N * DO);
    size_t o_w1lt   = alloc(DI * DH);
    size_t o_w1rt   = alloc(DI * DH);
    size_t o_w2lt   = alloc(DH * DO);
    size_t o_w2rt   = alloc(DH * DO);
    (void)ws_size;

    float* ws = (float*)d_ws;
    int*   cnt    = (int*)(ws + o_cnt);
    int*   rowptr = (int*)(ws + o_rowptr);
    int*   cursor = (int*)(ws + o_cursor);
    int*   col    = (int*)(ws + o_col);
    float* inv    = ws + o_inv;
    float* agg1   = ws + o_agg1;
    float* h      = ws + o_h;
    float* p2lp   = ws + o_p2lp;
    float* selfp  = ws + o_selfp;
    float* W1lT   = ws + o_w1lt;
    float* W1rT   = ws + o_w1rt;
    float* W2lT   = ws + o_w2lt;
    float* W2rT   = ws + o_w2rt;

    hipMemsetAsync(d_ws, 0, zero_floats * sizeof(float), stream);

    transpose_kernel<<<(DH * DI + 255) / 256, 256, 0, stream>>>(W1lT, W1l, DH, DI);
    transpose_kernel<<<(DH * DI + 255) / 256, 256, 0, stream>>>(W1rT, W1r, DH, DI);
    transpose_kernel<<<(DO * DH + 255) / 256, 256, 0, stream>>>(W2lT, W2l, DO, DH);
    transpose_kernel<<<(DO * DH + 255) / 256, 256, 0, stream>>>(W2rT, W2r, DO, DH);

    count_kernel<<<(E + 255) / 256, 256, 0, stream>>>(dst, cnt, E);
    scan_kernel<<<1, 1024, 0, stream>>>(cnt, rowptr, cursor, N);
    fill_kernel<<<(E + 255) / 256, 256, 0, stream>>>(src, dst, cursor, col, E);
    inv_kernel<<<(N + 255) / 256, 256, 0, stream>>>(cnt, inv, N);

    agg1_kernel<<<(N + 3) / 4, 256, 0, stream>>>(x, rowptr, cnt, inv, col, agg1, N);
    layer1_kernel<<<(N + 15) / 16, 256, 0, stream>>>(x, agg1, W1lT, W1rT, b1, h, N);
    precompute2_kernel<<<(N + 15) / 16, 256, 0, stream>>>(h, W2lT, W2rT, b2, p2lp, selfp, N);
    agg2_softmax_kernel<<<(N + 3) / 4, 256, 0, stream>>>(p2lp, selfp, rowptr, cnt, inv, col, out, N);
}

// Round 3
// 628.698 us; speedup vs baseline: 2.2891x; 1.3814x over previous
//
#include <hip/hip_runtime.h>
#include <math.h>

#define NN 100000
#define DI 64
#define DH 128
#define DO 40

// ---------- CSR build ----------

__global__ void count_kernel(const int* __restrict__ dst, int* __restrict__ cnt, int E) {
    int e = blockIdx.x * 256 + threadIdx.x;
    if (e < E) atomicAdd(&cnt[dst[e]], 1);
}

// phase 1: per-block sums of cnt
__global__ __launch_bounds__(256) void blocksum_kernel(const int* __restrict__ cnt,
                                                       int* __restrict__ blocksum, int N) {
    __shared__ int red[4];
    int t = threadIdx.x;
    int i = blockIdx.x * 256 + t;
    int v = (i < N) ? cnt[i] : 0;
#pragma unroll
    for (int off = 32; off >= 1; off >>= 1) v += __shfl_down(v, off, 64);
    if ((t & 63) == 0) red[t >> 6] = v;
    __syncthreads();
    if (t == 0) blocksum[blockIdx.x] = red[0] + red[1] + red[2] + red[3];
}

// phase 2: one block, exclusive scan of nb block sums (nb <= 512)
__global__ __launch_bounds__(512) void scanblocks_kernel(const int* __restrict__ blocksum,
                                                         int* __restrict__ blockoff, int nb) {
    __shared__ int s[512];
    int t = threadIdx.x;
    int v = (t < nb) ? blocksum[t] : 0;
    s[t] = v;
    __syncthreads();
    for (int off = 1; off < 512; off <<= 1) {
        int tmp = (t >= off) ? s[t - off] : 0;
        __syncthreads();
        s[t] += tmp;
        __syncthreads();
    }
    if (t < nb) blockoff[t] = s[t] - v;   // exclusive
}

// phase 3: block-local exclusive scan + block offset -> rowptr/cursor; fused inv
__global__ __launch_bounds__(256) void writeptr_kernel(const int* __restrict__ cnt,
                                                       const int* __restrict__ blockoff,
                                                       int* __restrict__ rowptr,
                                                       int* __restrict__ cursor,
                                                       float* __restrict__ inv, int N) {
    __shared__ int s[256];
    int t = threadIdx.x;
    int i = blockIdx.x * 256 + t;
    int v = (i < N) ? cnt[i] : 0;
    s[t] = v;
    __syncthreads();
    for (int off = 1; off < 256; off <<= 1) {
        int tmp = (t >= off) ? s[t - off] : 0;
        __syncthreads();
        s[t] += tmp;
        __syncthreads();
    }
    if (i < N) {
        int p = blockoff[blockIdx.x] + s[t] - v;
        rowptr[i] = p;
        cursor[i] = p;
        inv[i] = 1.0f / (float)(v > 0 ? v : 1);
    }
}

__global__ void fill_kernel(const int* __restrict__ src, const int* __restrict__ dst,
                            int* __restrict__ cursor, int* __restrict__ col, int E) {
    int e = blockIdx.x * 256 + threadIdx.x;
    if (e < E) {
        int pos = atomicAdd(&cursor[dst[e]], 1);
        col[pos] = src[e];
    }
}

// dst[c*rows + r] = src[r*cols + c]
__global__ void transpose_kernel(float* __restrict__ dstp, const float* __restrict__ srcp,
                                 int rows, int cols) {
    int i = blockIdx.x * 256 + threadIdx.x;
    if (i < rows * cols) {
        int r = i / cols, c = i - r * cols;
        dstp[c * rows + r] = srcp[i];
    }
}

// ---------- layer 1 ----------

// wave per node: agg1[n][lane] = inv[n] * sum_{i in row} x[col[i]][lane]
__global__ void agg1_kernel(const float* __restrict__ x, const int* __restrict__ rowptr,
                            const int* __restrict__ cnt, const float* __restrict__ inv,
                            const int* __restrict__ col, float* __restrict__ agg, int N) {
    int n = (blockIdx.x * 256 + threadIdx.x) >> 6;
    int lane = threadIdx.x & 63;
    if (n >= N) return;
    int beg = rowptr[n], deg = cnt[n];
    float acc = 0.f;
    int i = 0;
    for (; i + 4 <= deg; i += 4) {
        int s0 = col[beg + i], s1 = col[beg + i + 1];
        int s2 = col[beg + i + 2], s3 = col[beg + i + 3];
        float a = x[(size_t)s0 * DI + lane];
        float b = x[(size_t)s1 * DI + lane];
        float c = x[(size_t)s2 * DI + lane];
        float d = x[(size_t)s3 * DI + lane];
        acc += (a + b) + (c + d);
    }
    for (; i < deg; i++) acc += x[(size_t)col[beg + i] * DI + lane];
    agg[(size_t)n * DI + lane] = acc * inv[n];
}

// h[n] = relu( agg1[n] @ W1l^T + b1 + x[n] @ W1r^T )
__global__ __launch_bounds__(256) void layer1_kernel(
        const float* __restrict__ x, const float* __restrict__ agg,
        const float* __restrict__ W1lT, const float* __restrict__ W1rT,
        const float* __restrict__ b1, float* __restrict__ h, int N) {
    __shared__ float xs[16][DI];
    __shared__ float as[16][DI];
    int n0 = blockIdx.x * 16;
    int tid = threadIdx.x;
    for (int i = tid; i < 16 * DI; i += 256) {
        int t = i >> 6, k = i & 63;
        int n = n0 + t;
        float xv = 0.f, av = 0.f;
        if (n < N) {
            xv = x[(size_t)n * DI + k];
            av = agg[(size_t)n * DI + k];
        }
        xs[t][k] = xv; as[t][k] = av;
    }
    __syncthreads();
    int j = tid & 127, half = tid >> 7;
    float bj = b1[j];
    float acc[8];
#pragma unroll
    for (int t = 0; t < 8; t++) acc[t] = bj;
    for (int k = 0; k < DI; k++) {
        float wl = W1lT[k * DH + j];
        float wr = W1rT[k * DH + j];
#pragma unroll
        for (int t = 0; t < 8; t++)
            acc[t] += as[half * 8 + t][k] * wl + xs[half * 8 + t][k] * wr;
    }
#pragma unroll
    for (int t = 0; t < 8; t++) {
        int n = n0 + half * 8 + t;
        if (n < N) h[(size_t)n * DH + j] = fmaxf(acc[t], 0.f);
    }
}

// ---------- layer 2 (transform-then-aggregate) ----------

// p2lp[n][lane] = (lane<40) ? (W2l @ h[n])[lane] : 0   (padded to 64)
// selfp[n][j]   = (W2r @ h[n])[j] + b2[j]
__global__ __launch_bounds__(256) void precompute2_kernel(
        const float* __restrict__ h, const float* __restrict__ W2lT,
        const float* __restrict__ W2rT, const float* __restrict__ b2,
        float* __restrict__ p2lp, float* __restrict__ selfp, int N) {
    __shared__ float hs[16][DH];
    int n0 = blockIdx.x * 16;
    int tid = threadIdx.x;
    for (int i = tid; i < 16 * DH; i += 256) {
        int t = i >> 7, k = i & 127;
        int n = n0 + t;
        hs[t][k] = (n < N) ? h[(size_t)n * DH + k] : 0.f;
    }
    __syncthreads();
    int wave = tid >> 6, lane = tid & 63;
    float accl[4], accr[4];
    float bj = (lane < DO) ? b2[lane] : 0.f;
#pragma unroll
    for (int t = 0; t < 4; t++) { accl[t] = 0.f; accr[t] = bj; }
    if (lane < DO) {
        for (int k = 0; k < DH; k++) {
            float wl = W2lT[k * DO + lane];
            float wr = W2rT[k * DO + lane];
#pragma unroll
            for (int t = 0; t < 4; t++) {
                float hv = hs[wave * 4 + t][k];
                accl[t] += hv * wl;
                accr[t] += hv * wr;
            }
        }
    }
#pragma unroll
    for (int t = 0; t < 4; t++) {
        int n = n0 + wave * 4 + t;
        if (n < N) {
            p2lp[(size_t)n * 64 + lane] = (lane < DO) ? accl[t] : 0.f;
            if (lane < DO) selfp[(size_t)n * DO + lane] = accr[t];
        }
    }
}

// wave per node: out[n] = log_softmax( inv[n]*sum_{i} p2lp[col[i]] + selfp[n] )
__global__ void agg2_softmax_kernel(const float* __restrict__ p2lp,
                                    const float* __restrict__ selfp,
                                    const int* __restrict__ rowptr,
                                    const int* __restrict__ cnt,
                                    const float* __restrict__ inv,
                                    const int* __restrict__ col,
                                    float* __restrict__ out, int N) {
    int n = (blockIdx.x * 256 + threadIdx.x) >> 6;
    int lane = threadIdx.x & 63;
    if (n >= N) return;
    int beg = rowptr[n], deg = cnt[n];
    float acc = 0.f;
    int i = 0;
    for (; i + 4 <= deg; i += 4) {
        int s0 = col[beg + i], s1 = col[beg + i + 1];
        int s2 = col[beg + i + 2], s3 = col[beg + i + 3];
        float a = p2lp[(size_t)s0 * 64 + lane];
        float b = p2lp[(size_t)s1 * 64 + lane];
        float c = p2lp[(size_t)s2 * 64 + lane];
        float d = p2lp[(size_t)s3 * 64 + lane];
        acc += (a + b) + (c + d);
    }
    for (; i < deg; i++) acc += p2lp[(size_t)col[beg + i] * 64 + lane];
    float v = acc * inv[n];
    if (lane < DO) v += selfp[(size_t)n * DO + lane];
    float val = (lane < DO) ? v : -INFINITY;
    float m = val;
#pragma unroll
    for (int off = 32; off >= 1; off >>= 1) m = fmaxf(m, __shfl_xor(m, off, 64));
    float ex = (lane < DO) ? expf(v - m) : 0.f;
    float s = ex;
#pragma unroll
    for (int off = 32; off >= 1; off >>= 1) s += __shfl_xor(s, off, 64);
    if (lane < DO) out[(size_t)n * DO + lane] = v - m - logf(s);
}

extern "C" void kernel_launch(void* const* d_in, const int* in_sizes, int n_in,
                              void* d_out, int out_size, void* d_ws, size_t ws_size,
                              hipStream_t stream) {
    const float* x   = (const float*)d_in[0];
    const int*  ei   = (const int*)d_in[1];
    const float* W1l = (const float*)d_in[2];
    const float* b1  = (const float*)d_in[3];
    const float* W1r = (const float*)d_in[4];
    const float* W2l = (const float*)d_in[5];
    const float* b2  = (const float*)d_in[6];
    const float* W2r = (const float*)d_in[7];
    float* out = (float*)d_out;

    const int E = in_sizes[1] / 2;
    const int N = NN;
    const int* src = ei;
    const int* dst = ei + E;
    const int nb = (N + 255) / 256;   // 391 scan blocks

    size_t off = 0;
    auto alloc = [&](size_t nf) { size_t o = off; off += (nf + 63) & ~(size_t)63; return o; };
    size_t o_cnt    = alloc(N);            // int, zeroed
    size_t zero_floats = off;
    size_t o_bsum   = alloc(nb);           // int
    size_t o_boff   = alloc(nb);           // int
    size_t o_rowptr = alloc(N + 1);        // int
    size_t o_cursor = alloc(N);            // int
    size_t o_col    = alloc(E);            // int
    size_t o_inv    = alloc(N);
    size_t o_agg1   = alloc((size_t)N * DI);
    size_t o_h      = alloc((size_t)N * DH);
    size_t o_p2lp   = alloc((size_t)N * 64);
    size_t o_selfp  = alloc((size_t)N * DO);
    size_t o_w1lt   = alloc(DI * DH);
    size_t o_w1rt   = alloc(DI * DH);
    size_t o_w2lt   = alloc(DH * DO);
    size_t o_w2rt   = alloc(DH * DO);
    (void)ws_size;

    float* ws = (float*)d_ws;
    int*   cnt    = (int*)(ws + o_cnt);
    int*   bsum   = (int*)(ws + o_bsum);
    int*   boff   = (int*)(ws + o_boff);
    int*   rowptr = (int*)(ws + o_rowptr);
    int*   cursor = (int*)(ws + o_cursor);
    int*   col    = (int*)(ws + o_col);
    float* inv    = ws + o_inv;
    float* agg1   = ws + o_agg1;
    float* h      = ws + o_h;
    float* p2lp   = ws + o_p2lp;
    float* selfp  = ws + o_selfp;
    float* W1lT   = ws + o_w1lt;
    float* W1rT   = ws + o_w1rt;
    float* W2lT   = ws + o_w2lt;
    float* W2rT   = ws + o_w2rt;

    hipMemsetAsync(d_ws, 0, zero_floats * sizeof(float), stream);

    transpose_kernel<<<(DH * DI + 255) / 256, 256, 0, stream>>>(W1lT, W1l, DH, DI);
    transpose_kernel<<<(DH * DI + 255) / 256, 256, 0, stream>>>(W1rT, W1r, DH, DI);
    transpose_kernel<<<(DO * DH + 255) / 256, 256, 0, stream>>>(W2lT, W2l, DO, DH);
    transpose_kernel<<<(DO * DH + 255) / 256, 256, 0, stream>>>(W2rT, W2r, DO, DH);

    count_kernel<<<(E + 255) / 256, 256, 0, stream>>>(dst, cnt, E);
    blocksum_kernel<<<nb, 256, 0, stream>>>(cnt, bsum, N);
    scanblocks_kernel<<<1, 512, 0, stream>>>(bsum, boff, nb);
    writeptr_kernel<<<nb, 256, 0, stream>>>(cnt, boff, rowptr, cursor, inv, N);
    fill_kernel<<<(E + 255) / 256, 256, 0, stream>>>(src, dst, cursor, col, E);

    agg1_kernel<<<(N + 3) / 4, 256, 0, stream>>>(x, rowptr, cnt, inv, col, agg1, N);
    layer1_kernel<<<(N + 15) / 16, 256, 0, stream>>>(x, agg1, W1lT, W1rT, b1, h, N);
    precompute2_kernel<<<(N + 15) / 16, 256, 0, stream>>>(h, W2lT, W2rT, b2, p2lp, selfp, N);
    agg2_softmax_kernel<<<(N + 3) / 4, 256, 0, stream>>>(p2lp, selfp, rowptr, cnt, inv, col, out, N);
}

// Round 4
// 493.171 us; speedup vs baseline: 2.9182x; 1.2748x over previous
//
#include <hip/hip_runtime.h>
#include <math.h>

#define NN 100000
#define DI 64
#define DH 128
#define DO 40

#define NBUCK 512
#define NPB 196          // nodes per bucket: 512*196 = 100352 >= 100000
#define EPB 8192         // edges per block in bucket count/scatter

// ---------- bucketed CSR build ----------

// K1: global bucket histogram via LDS privatization
__global__ __launch_bounds__(256) void bucket_count_kernel(const int* __restrict__ dst,
                                                           int* __restrict__ bcnt, int E) {
    __shared__ int h[NBUCK];
    int t = threadIdx.x;
    for (int i = t; i < NBUCK; i += 256) h[i] = 0;
    __syncthreads();
    int base = blockIdx.x * EPB;
    int end = base + EPB; if (end > E) end = E;
    for (int i = base + t; i < end; i += 256)
        atomicAdd(&h[(unsigned)dst[i] / NPB], 1);
    __syncthreads();
    for (int i = t; i < NBUCK; i += 256) {
        int v = h[i];
        if (v) atomicAdd(&bcnt[i], v);
    }
}

// K2: one block, exclusive scan of 512 bucket counts -> bbase, bcur
__global__ __launch_bounds__(512) void bucket_scan_kernel(const int* __restrict__ bcnt,
                                                          int* __restrict__ bbase,
                                                          int* __restrict__ bcur, int E) {
    __shared__ int s[NBUCK];
    int t = threadIdx.x;
    int v = bcnt[t];
    s[t] = v;
    __syncthreads();
    for (int off = 1; off < NBUCK; off <<= 1) {
        int tmp = (t >= off) ? s[t - off] : 0;
        __syncthreads();
        s[t] += tmp;
        __syncthreads();
    }
    int excl = s[t] - v;
    bbase[t] = excl;
    bcur[t] = excl;
    if (t == 0) bbase[NBUCK] = E;
}

// K3: scatter edges into bucket-contiguous regions, packed (local<<17)|src
__global__ __launch_bounds__(256) void bucket_scatter_kernel(const int* __restrict__ src,
                                                             const int* __restrict__ dst,
                                                             int* __restrict__ bcur,
                                                             int* __restrict__ eb, int E) {
    __shared__ int h[NBUCK];
    int t = threadIdx.x;
    for (int i = t; i < NBUCK; i += 256) h[i] = 0;
    __syncthreads();
    int base = blockIdx.x * EPB;
    int end = base + EPB; if (end > E) end = E;
    for (int i = base + t; i < end; i += 256)
        atomicAdd(&h[(unsigned)dst[i] / NPB], 1);
    __syncthreads();
    // reserve a contiguous range per bucket for this block; h becomes cursor
    for (int i = t; i < NBUCK; i += 256) {
        int v = h[i];
        h[i] = v ? atomicAdd(&bcur[i], v) : 0;
    }
    __syncthreads();
    for (int i = base + t; i < end; i += 256) {
        int d = dst[i];
        unsigned bk = (unsigned)d / NPB;
        int local = d - (int)bk * NPB;
        int pos = atomicAdd(&h[bk], 1);           // LDS atomic, global position
        eb[pos] = (local << 17) | src[i];
    }
}

// K4: one block per bucket: local count + scan -> rowptr/cnt/inv + dense col fill
__global__ __launch_bounds__(256) void bucket_fill_kernel(const int* __restrict__ eb,
                                                          const int* __restrict__ bbase,
                                                          int* __restrict__ rowptr,
                                                          int* __restrict__ cntg,
                                                          float* __restrict__ inv,
                                                          int* __restrict__ col, int N) {
    __shared__ int scnt[256];
    __shared__ int scur[256];
    int b = blockIdx.x, t = threadIdx.x;
    int ebeg = bbase[b], eend = bbase[b + 1];
    int nb0 = b * NPB;
    scnt[t] = 0;
    __syncthreads();
    for (int i = ebeg + t; i < eend; i += 256)
        atomicAdd(&scnt[eb[i] >> 17], 1);
    __syncthreads();
    int myc = scnt[t];
    // inclusive scan over 256 entries
    for (int off = 1; off < 256; off <<= 1) {
        int tmp = (t >= off) ? scnt[t - off] : 0;
        __syncthreads();
        scnt[t] += tmp;
        __syncthreads();
    }
    int excl = scnt[t] - myc;
    int node = nb0 + t;
    if (t < NPB && node < N) {
        rowptr[node] = ebeg + excl;
        cntg[node] = myc;
        inv[node] = 1.0f / (float)(myc > 0 ? myc : 1);
    }
    scur[t] = ebeg + excl;
    __syncthreads();
    for (int i = ebeg + t; i < eend; i += 256) {
        int pk = eb[i];
        int l = pk >> 17, s = pk & 0x1FFFF;
        int pos = atomicAdd(&scur[l], 1);
        col[pos] = s;
    }
}

// fused weight transposes
__global__ void transpose_all_kernel(const float* __restrict__ W1l, const float* __restrict__ W1r,
                                     const float* __restrict__ W2l, const float* __restrict__ W2r,
                                     float* __restrict__ W1lT, float* __restrict__ W1rT,
                                     float* __restrict__ W2lT, float* __restrict__ W2rT) {
    int i = blockIdx.x * 256 + threadIdx.x;
    if (i < DH * DI) {                       // 8192
        int r = i >> 6, c = i & 63;
        W1lT[c * DH + r] = W1l[i];
        W1rT[c * DH + r] = W1r[i];
    }
    if (i < DO * DH) {                       // 5120
        int r = i / DH, c = i - r * DH;
        W2lT[c * DO + r] = W2l[i];
        W2rT[c * DO + r] = W2r[i];
    }
}

// ---------- layer 1 ----------

// wave per node: agg1[n][lane] = inv[n] * sum_{i in row} x[col[i]][lane]
__global__ void agg1_kernel(const float* __restrict__ x, const int* __restrict__ rowptr,
                            const int* __restrict__ cnt, const float* __restrict__ inv,
                            const int* __restrict__ col, float* __restrict__ agg, int N) {
    int n = (blockIdx.x * 256 + threadIdx.x) >> 6;
    int lane = threadIdx.x & 63;
    if (n >= N) return;
    int beg = rowptr[n], deg = cnt[n];
    float acc = 0.f;
    int i = 0;
    for (; i + 4 <= deg; i += 4) {
        int s0 = col[beg + i], s1 = col[beg + i + 1];
        int s2 = col[beg + i + 2], s3 = col[beg + i + 3];
        float a = x[(size_t)s0 * DI + lane];
        float b = x[(size_t)s1 * DI + lane];
        float c = x[(size_t)s2 * DI + lane];
        float d = x[(size_t)s3 * DI + lane];
        acc += (a + b) + (c + d);
    }
    for (; i < deg; i++) acc += x[(size_t)col[beg + i] * DI + lane];
    agg[(size_t)n * DI + lane] = acc * inv[n];
}

// h[n] = relu( agg1[n] @ W1l^T + b1 + x[n] @ W1r^T )
__global__ __launch_bounds__(256) void layer1_kernel(
        const float* __restrict__ x, const float* __restrict__ agg,
        const float* __restrict__ W1lT, const float* __restrict__ W1rT,
        const float* __restrict__ b1, float* __restrict__ h, int N) {
    __shared__ float xs[16][DI];
    __shared__ float as[16][DI];
    int n0 = blockIdx.x * 16;
    int tid = threadIdx.x;
    for (int i = tid; i < 16 * DI; i += 256) {
        int t = i >> 6, k = i & 63;
        int n = n0 + t;
        float xv = 0.f, av = 0.f;
        if (n < N) {
            xv = x[(size_t)n * DI + k];
            av = agg[(size_t)n * DI + k];
        }
        xs[t][k] = xv; as[t][k] = av;
    }
    __syncthreads();
    int j = tid & 127, half = tid >> 7;
    float bj = b1[j];
    float acc[8];
#pragma unroll
    for (int t = 0; t < 8; t++) acc[t] = bj;
    for (int k = 0; k < DI; k++) {
        float wl = W1lT[k * DH + j];
        float wr = W1rT[k * DH + j];
#pragma unroll
        for (int t = 0; t < 8; t++)
            acc[t] += as[half * 8 + t][k] * wl + xs[half * 8 + t][k] * wr;
    }
#pragma unroll
    for (int t = 0; t < 8; t++) {
        int n = n0 + half * 8 + t;
        if (n < N) h[(size_t)n * DH + j] = fmaxf(acc[t], 0.f);
    }
}

// ---------- layer 2 (transform-then-aggregate) ----------

__global__ __launch_bounds__(256) void precompute2_kernel(
        const float* __restrict__ h, const float* __restrict__ W2lT,
        const float* __restrict__ W2rT, const float* __restrict__ b2,
        float* __restrict__ p2lp, float* __restrict__ selfp, int N) {
    __shared__ float hs[16][DH];
    int n0 = blockIdx.x * 16;
    int tid = threadIdx.x;
    for (int i = tid; i < 16 * DH; i += 256) {
        int t = i >> 7, k = i & 127;
        int n = n0 + t;
        hs[t][k] = (n < N) ? h[(size_t)n * DH + k] : 0.f;
    }
    __syncthreads();
    int wave = tid >> 6, lane = tid & 63;
    float accl[4], accr[4];
    float bj = (lane < DO) ? b2[lane] : 0.f;
#pragma unroll
    for (int t = 0; t < 4; t++) { accl[t] = 0.f; accr[t] = bj; }
    if (lane < DO) {
        for (int k = 0; k < DH; k++) {
            float wl = W2lT[k * DO + lane];
            float wr = W2rT[k * DO + lane];
#pragma unroll
            for (int t = 0; t < 4; t++) {
                float hv = hs[wave * 4 + t][k];
                accl[t] += hv * wl;
                accr[t] += hv * wr;
            }
        }
    }
#pragma unroll
    for (int t = 0; t < 4; t++) {
        int n = n0 + wave * 4 + t;
        if (n < N) {
            p2lp[(size_t)n * 64 + lane] = (lane < DO) ? accl[t] : 0.f;
            if (lane < DO) selfp[(size_t)n * DO + lane] = accr[t];
        }
    }
}

// wave per node: out[n] = log_softmax( inv[n]*sum_{i} p2lp[col[i]] + selfp[n] )
__global__ void agg2_softmax_kernel(const float* __restrict__ p2lp,
                                    const float* __restrict__ selfp,
                                    const int* __restrict__ rowptr,
                                    const int* __restrict__ cnt,
                                    const float* __restrict__ inv,
                                    const int* __restrict__ col,
                                    float* __restrict__ out, int N) {
    int n = (blockIdx.x * 256 + threadIdx.x) >> 6;
    int lane = threadIdx.x & 63;
    if (n >= N) return;
    int beg = rowptr[n], deg = cnt[n];
    float acc = 0.f;
    int i = 0;
    for (; i + 4 <= deg; i += 4) {
        int s0 = col[beg + i], s1 = col[beg + i + 1];
        int s2 = col[beg + i + 2], s3 = col[beg + i + 3];
        float a = p2lp[(size_t)s0 * 64 + lane];
        float b = p2lp[(size_t)s1 * 64 + lane];
        float c = p2lp[(size_t)s2 * 64 + lane];
        float d = p2lp[(size_t)s3 * 64 + lane];
        acc += (a + b) + (c + d);
    }
    for (; i < deg; i++) acc += p2lp[(size_t)col[beg + i] * 64 + lane];
    float v = acc * inv[n];
    if (lane < DO) v += selfp[(size_t)n * DO + lane];
    float val = (lane < DO) ? v : -INFINITY;
    float m = val;
#pragma unroll
    for (int off = 32; off >= 1; off >>= 1) m = fmaxf(m, __shfl_xor(m, off, 64));
    float ex = (lane < DO) ? expf(v - m) : 0.f;
    float s = ex;
#pragma unroll
    for (int off = 32; off >= 1; off >>= 1) s += __shfl_xor(s, off, 64);
    if (lane < DO) out[(size_t)n * DO + lane] = v - m - logf(s);
}

extern "C" void kernel_launch(void* const* d_in, const int* in_sizes, int n_in,
                              void* d_out, int out_size, void* d_ws, size_t ws_size,
                              hipStream_t stream) {
    const float* x   = (const float*)d_in[0];
    const int*  ei   = (const int*)d_in[1];
    const float* W1l = (const float*)d_in[2];
    const float* b1  = (const float*)d_in[3];
    const float* W1r = (const float*)d_in[4];
    const float* W2l = (const float*)d_in[5];
    const float* b2  = (const float*)d_in[6];
    const float* W2r = (const float*)d_in[7];
    float* out = (float*)d_out;

    const int E = in_sizes[1] / 2;
    const int N = NN;
    const int* src = ei;
    const int* dst = ei + E;
    const int nbe = (E + EPB - 1) / EPB;   // edge-blocks for bucket count/scatter

    size_t off = 0;
    auto alloc = [&](size_t nf) { size_t o = off; off += (nf + 63) & ~(size_t)63; return o; };
    size_t o_bcnt   = alloc(NBUCK);        // int, zeroed
    size_t zero_floats = off;
    size_t o_bbase  = alloc(NBUCK + 1);    // int
    size_t o_bcur   = alloc(NBUCK);        // int
    size_t o_eb     = alloc(E);            // int (packed edges)
    size_t o_rowptr = alloc(N);            // int
    size_t o_cnt    = alloc(N);            // int
    size_t o_col    = alloc(E);            // int
    size_t o_inv    = alloc(N);
    size_t o_agg1   = alloc((size_t)N * DI);
    size_t o_h      = alloc((size_t)N * DH);
    size_t o_p2lp   = alloc((size_t)N * 64);
    size_t o_selfp  = alloc((size_t)N * DO);
    size_t o_w1lt   = alloc(DI * DH);
    size_t o_w1rt   = alloc(DI * DH);
    size_t o_w2lt   = alloc(DH * DO);
    size_t o_w2rt   = alloc(DH * DO);
    (void)ws_size;

    float* ws = (float*)d_ws;
    int*   bcnt   = (int*)(ws + o_bcnt);
    int*   bbase  = (int*)(ws + o_bbase);
    int*   bcur   = (int*)(ws + o_bcur);
    int*   eb     = (int*)(ws + o_eb);
    int*   rowptr = (int*)(ws + o_rowptr);
    int*   cnt    = (int*)(ws + o_cnt);
    int*   col    = (int*)(ws + o_col);
    float* inv    = ws + o_inv;
    float* agg1   = ws + o_agg1;
    float* h      = ws + o_h;
    float* p2lp   = ws + o_p2lp;
    float* selfp  = ws + o_selfp;
    float* W1lT   = ws + o_w1lt;
    float* W1rT   = ws + o_w1rt;
    float* W2lT   = ws + o_w2lt;
    float* W2rT   = ws + o_w2rt;

    hipMemsetAsync(d_ws, 0, zero_floats * sizeof(float), stream);

    transpose_all_kernel<<<(DH * DI + 255) / 256, 256, 0, stream>>>(
        W1l, W1r, W2l, W2r, W1lT, W1rT, W2lT, W2rT);

    bucket_count_kernel<<<nbe, 256, 0, stream>>>(dst, bcnt, E);
    bucket_scan_kernel<<<1, NBUCK, 0, stream>>>(bcnt, bbase, bcur, E);
    bucket_scatter_kernel<<<nbe, 256, 0, stream>>>(src, dst, bcur, eb, E);
    bucket_fill_kernel<<<NBUCK, 256, 0, stream>>>(eb, bbase, rowptr, cnt, inv, col, N);

    agg1_kernel<<<(N + 3) / 4, 256, 0, stream>>>(x, rowptr, cnt, inv, col, agg1, N);
    layer1_kernel<<<(N + 15) / 16, 256, 0, stream>>>(x, agg1, W1lT, W1rT, b1, h, N);
    precompute2_kernel<<<(N + 15) / 16, 256, 0, stream>>>(h, W2lT, W2rT, b2, p2lp, selfp, N);
    agg2_softmax_kernel<<<(N + 3) / 4, 256, 0, stream>>>(p2lp, selfp, rowptr, cnt, inv, col, out, N);
}

// Round 5
// 320.023 us; speedup vs baseline: 4.4970x; 1.5410x over previous
//
#include <hip/hip_runtime.h>
#include <math.h>

#define NN 100000
#define DI 64
#define DH 128
#define DO 40

#define NBUCK 512
#define NPB 196          // nodes per bucket: 512*196 = 100352 >= 100000
#define EPB 8192         // edges per block in bucket count/scatter

typedef __attribute__((ext_vector_type(8))) short bf16x8;
typedef __attribute__((ext_vector_type(4))) float f32x4;

__device__ __forceinline__ unsigned short bf16r(float a) {
    unsigned u = __float_as_uint(a);
    u = (u + 0x7FFF + ((u >> 16) & 1)) >> 16;
    return (unsigned short)u;
}
__device__ __forceinline__ unsigned bf16pair(float a, float b) {
    return (unsigned)bf16r(a) | ((unsigned)bf16r(b) << 16);
}
__device__ __forceinline__ float bflo(unsigned u) { return __uint_as_float(u << 16); }
__device__ __forceinline__ float bfhi(unsigned u) { return __uint_as_float(u & 0xFFFF0000u); }

// ---------- bucketed CSR build (unchanged from R4) ----------

__global__ __launch_bounds__(256) void bucket_count_kernel(const int* __restrict__ dst,
                                                           int* __restrict__ bcnt, int E) {
    __shared__ int h[NBUCK];
    int t = threadIdx.x;
    for (int i = t; i < NBUCK; i += 256) h[i] = 0;
    __syncthreads();
    int base = blockIdx.x * EPB;
    int end = base + EPB; if (end > E) end = E;
    for (int i = base + t; i < end; i += 256)
        atomicAdd(&h[(unsigned)dst[i] / NPB], 1);
    __syncthreads();
    for (int i = t; i < NBUCK; i += 256) {
        int v = h[i];
        if (v) atomicAdd(&bcnt[i], v);
    }
}

__global__ __launch_bounds__(512) void bucket_scan_kernel(const int* __restrict__ bcnt,
                                                          int* __restrict__ bbase,
                                                          int* __restrict__ bcur, int E) {
    __shared__ int s[NBUCK];
    int t = threadIdx.x;
    int v = bcnt[t];
    s[t] = v;
    __syncthreads();
    for (int off = 1; off < NBUCK; off <<= 1) {
        int tmp = (t >= off) ? s[t - off] : 0;
        __syncthreads();
        s[t] += tmp;
        __syncthreads();
    }
    int excl = s[t] - v;
    bbase[t] = excl;
    bcur[t] = excl;
    if (t == 0) bbase[NBUCK] = E;
}

__global__ __launch_bounds__(256) void bucket_scatter_kernel(const int* __restrict__ src,
                                                             const int* __restrict__ dst,
                                                             int* __restrict__ bcur,
                                                             int* __restrict__ eb, int E) {
    __shared__ int h[NBUCK];
    int t = threadIdx.x;
    for (int i = t; i < NBUCK; i += 256) h[i] = 0;
    __syncthreads();
    int base = blockIdx.x * EPB;
    int end = base + EPB; if (end > E) end = E;
    for (int i = base + t; i < end; i += 256)
        atomicAdd(&h[(unsigned)dst[i] / NPB], 1);
    __syncthreads();
    for (int i = t; i < NBUCK; i += 256) {
        int v = h[i];
        h[i] = v ? atomicAdd(&bcur[i], v) : 0;
    }
    __syncthreads();
    for (int i = base + t; i < end; i += 256) {
        int d = dst[i];
        unsigned bk = (unsigned)d / NPB;
        int local = d - (int)bk * NPB;
        int pos = atomicAdd(&h[bk], 1);
        eb[pos] = (local << 17) | src[i];
    }
}

__global__ __launch_bounds__(256) void bucket_fill_kernel(const int* __restrict__ eb,
                                                          const int* __restrict__ bbase,
                                                          int* __restrict__ rowptr,
                                                          int* __restrict__ cntg,
                                                          float* __restrict__ inv,
                                                          int* __restrict__ col, int N) {
    __shared__ int scnt[256];
    __shared__ int scur[256];
    int b = blockIdx.x, t = threadIdx.x;
    int ebeg = bbase[b], eend = bbase[b + 1];
    int nb0 = b * NPB;
    scnt[t] = 0;
    __syncthreads();
    for (int i = ebeg + t; i < eend; i += 256)
        atomicAdd(&scnt[eb[i] >> 17], 1);
    __syncthreads();
    int myc = scnt[t];
    for (int off = 1; off < 256; off <<= 1) {
        int tmp = (t >= off) ? scnt[t - off] : 0;
        __syncthreads();
        scnt[t] += tmp;
        __syncthreads();
    }
    int excl = scnt[t] - myc;
    int node = nb0 + t;
    if (t < NPB && node < N) {
        rowptr[node] = ebeg + excl;
        cntg[node] = myc;
        inv[node] = 1.0f / (float)(myc > 0 ? myc : 1);
    }
    scur[t] = ebeg + excl;
    __syncthreads();
    for (int i = ebeg + t; i < eend; i += 256) {
        int pk = eb[i];
        int l = pk >> 17, s = pk & 0x1FFFF;
        int pos = atomicAdd(&scur[l], 1);
        col[pos] = s;
    }
}

// ---------- weight prep: pack B-fragments (bf16) ----------
// WB1: nt(8) x ks(4) x lane(64) x j(8); value = Wcat1[k][n],
//   k = ks*32 + (lane>>4)*8 + j, n = nt*16 + (lane&15)
//   Wcat1[k][n] = k<64 ? W1l[n*64+k] : W1r[n*64+k-64]
// WB2: nt(5) x ks(4) x lane(64) x j(8); n<40 -> W2l[n*128+k] else W2r[(n-40)*128+k]
__global__ __launch_bounds__(256) void prep_weights_kernel(
        const float* __restrict__ W1l, const float* __restrict__ W1r,
        const float* __restrict__ W2l, const float* __restrict__ W2r,
        unsigned short* __restrict__ WB1, unsigned short* __restrict__ WB2) {
    int idx = blockIdx.x * 256 + threadIdx.x;
    if (idx < 16384) {
        int j = idx & 7, lane = (idx >> 3) & 63, ks = (idx >> 9) & 3, nt = idx >> 11;
        int k = ks * 32 + (lane >> 4) * 8 + j;
        int n = nt * 16 + (lane & 15);
        float v = (k < DI) ? W1l[n * DI + k] : W1r[n * DI + (k - DI)];
        WB1[idx] = bf16r(v);
    }
    int idx2 = idx - 16384;
    if (idx2 >= 0 && idx2 < 10240) {
        int j = idx2 & 7, lane = (idx2 >> 3) & 63, ks = (idx2 >> 9) & 3, nt = idx2 >> 11;
        int k = ks * 32 + (lane >> 4) * 8 + j;
        int n = nt * 16 + (lane & 15);
        float v = (n < DO) ? W2l[n * DH + k] : W2r[(n - DO) * DH + k];
        WB2[idx2] = bf16r(v);
    }
}

// x (f32, N x 64) -> xb (bf16 pairs as u32, N x 32)
__global__ void xconv_kernel(const float* __restrict__ x, unsigned* __restrict__ xb, int N) {
    int idx = blockIdx.x * 256 + threadIdx.x;
    if (idx < N * 32) {
        float2 f = ((const float2*)x)[idx];
        xb[idx] = bf16pair(f.x, f.y);
    }
}

// ---------- agg1: wave/node, half-wave per edge; writes xa = [mean | self] bf16 ----------
__global__ void agg1_kernel(const unsigned* __restrict__ xb, const int* __restrict__ rowptr,
                            const int* __restrict__ cnt, const float* __restrict__ inv,
                            const int* __restrict__ col, unsigned* __restrict__ xa, int N) {
    int n = (blockIdx.x * 256 + threadIdx.x) >> 6;
    int lane = threadIdx.x & 63;
    if (n >= N) return;
    int half = lane >> 5, l = lane & 31;
    int beg = rowptr[n], deg = cnt[n];
    float ax = 0.f, ay = 0.f;
    int i = 0;
    for (; i + 4 <= deg; i += 4) {
        int s0 = col[beg + i + half];
        int s1 = col[beg + i + 2 + half];
        unsigned u0 = xb[(size_t)s0 * 32 + l];
        unsigned u1 = xb[(size_t)s1 * 32 + l];
        ax += bflo(u0) + bflo(u1);
        ay += bfhi(u0) + bfhi(u1);
    }
    for (; i + 2 <= deg; i += 2) {
        int s0 = col[beg + i + half];
        unsigned u0 = xb[(size_t)s0 * 32 + l];
        ax += bflo(u0); ay += bfhi(u0);
    }
    if (i < deg && half == 0) {
        unsigned u0 = xb[(size_t)col[beg + i] * 32 + l];
        ax += bflo(u0); ay += bfhi(u0);
    }
    ax += __shfl_xor(ax, 32, 64);
    ay += __shfl_xor(ay, 32, 64);
    float invn = inv[n];
    if (half == 0) {
        xa[(size_t)n * 64 + l] = bf16pair(ax * invn, ay * invn);
    } else {
        xa[(size_t)n * 64 + 32 + l] = xb[(size_t)n * 32 + l];
    }
}

// ---------- GEMM1: h = relu(xa @ Wcat1 + b1), bf16 MFMA, no LDS ----------
__global__ __launch_bounds__(256) void gemm1_kernel(const unsigned short* __restrict__ xa,
                                                    const unsigned short* __restrict__ WB1,
                                                    const float* __restrict__ b1,
                                                    unsigned short* __restrict__ h, int N) {
    int w = threadIdx.x >> 6, lane = threadIdx.x & 63;
    int quad = lane >> 4, m = lane & 15;
    int rbase = blockIdx.x * 64 + w * 16;
    int arow = rbase + m; if (arow >= N) arow = N - 1;

    f32x4 acc[8];
#pragma unroll
    for (int nt = 0; nt < 8; nt++) acc[nt] = (f32x4)(0.f);

#pragma unroll
    for (int ks = 0; ks < 4; ks++) {
        bf16x8 a = *(const bf16x8*)(xa + (size_t)arow * 128 + ks * 32 + quad * 8);
#pragma unroll
        for (int nt = 0; nt < 8; nt++) {
            bf16x8 b = *(const bf16x8*)(WB1 + ((size_t)(nt * 4 + ks) * 64 + lane) * 8);
            acc[nt] = __builtin_amdgcn_mfma_f32_16x16x32_bf16(a, b, acc[nt], 0, 0, 0);
        }
    }
#pragma unroll
    for (int nt = 0; nt < 8; nt++) {
        int colj = nt * 16 + m;
        float bj = b1[colj];
#pragma unroll
        for (int r = 0; r < 4; r++) {
            int row = rbase + quad * 4 + r;
            if (row < N) {
                float v = acc[nt][r] + bj;
                h[(size_t)row * 128 + colj] = bf16r(fmaxf(v, 0.f));
            }
        }
    }
}

// ---------- GEMM2: [p2l | selfp] = h @ Wcat2 (+ b2 on selfp part) ----------
__global__ __launch_bounds__(256) void gemm2_kernel(const unsigned short* __restrict__ h,
                                                    const unsigned short* __restrict__ WB2,
                                                    const float* __restrict__ b2,
                                                    unsigned short* __restrict__ p2lp,
                                                    float* __restrict__ selfp, int N) {
    int w = threadIdx.x >> 6, lane = threadIdx.x & 63;
    int quad = lane >> 4, m = lane & 15;
    int rbase = blockIdx.x * 64 + w * 16;
    int arow = rbase + m; if (arow >= N) arow = N - 1;

    f32x4 acc[5];
#pragma unroll
    for (int nt = 0; nt < 5; nt++) acc[nt] = (f32x4)(0.f);

#pragma unroll
    for (int ks = 0; ks < 4; ks++) {
        bf16x8 a = *(const bf16x8*)(h + (size_t)arow * 128 + ks * 32 + quad * 8);
#pragma unroll
        for (int nt = 0; nt < 5; nt++) {
            bf16x8 b = *(const bf16x8*)(WB2 + ((size_t)(nt * 4 + ks) * 64 + lane) * 8);
            acc[nt] = __builtin_amdgcn_mfma_f32_16x16x32_bf16(a, b, acc[nt], 0, 0, 0);
        }
    }
#pragma unroll
    for (int nt = 0; nt < 5; nt++) {
        int colj = nt * 16 + m;
#pragma unroll
        for (int r = 0; r < 4; r++) {
            int row = rbase + quad * 4 + r;
            if (row < N) {
                float v = acc[nt][r];
                if (colj < DO) {
                    p2lp[(size_t)row * 64 + colj] = bf16r(v);
                } else {
                    selfp[(size_t)row * DO + (colj - DO)] = v + b2[colj - DO];
                    if (colj < 64) p2lp[(size_t)row * 64 + colj] = 0;
                }
            }
        }
    }
}

// ---------- agg2 + log_softmax: wave/node, half-wave per edge ----------
__global__ void agg2_softmax_kernel(const unsigned* __restrict__ p2lp,
                                    const float* __restrict__ selfp,
                                    const int* __restrict__ rowptr,
                                    const int* __restrict__ cnt,
                                    const float* __restrict__ inv,
                                    const int* __restrict__ col,
                                    float* __restrict__ out, int N) {
    int n = (blockIdx.x * 256 + threadIdx.x) >> 6;
    int lane = threadIdx.x & 63;
    if (n >= N) return;
    int half = lane >> 5, l = lane & 31;
    int beg = rowptr[n], deg = cnt[n];
    float ax = 0.f, ay = 0.f;
    int i = 0;
    for (; i + 4 <= deg; i += 4) {
        int s0 = col[beg + i + half];
        int s1 = col[beg + i + 2 + half];
        unsigned u0 = p2lp[(size_t)s0 * 32 + l];
        unsigned u1 = p2lp[(size_t)s1 * 32 + l];
        ax += bflo(u0) + bflo(u1);
        ay += bfhi(u0) + bfhi(u1);
    }
    for (; i + 2 <= deg; i += 2) {
        int s0 = col[beg + i + half];
        unsigned u0 = p2lp[(size_t)s0 * 32 + l];
        ax += bflo(u0); ay += bfhi(u0);
    }
    if (i < deg && half == 0) {
        unsigned u0 = p2lp[(size_t)col[beg + i] * 32 + l];
        ax += bflo(u0); ay += bfhi(u0);
    }
    ax += __shfl_xor(ax, 32, 64);
    ay += __shfl_xor(ay, 32, 64);
    float invn = inv[n];
    bool valid = (half == 0) && (l < 20);
    float vx = 0.f, vy = 0.f;
    if (valid) {
        float2 sp = *(const float2*)(selfp + (size_t)n * DO + 2 * l);
        vx = ax * invn + sp.x;
        vy = ay * invn + sp.y;
    }
    float mv = valid ? fmaxf(vx, vy) : -INFINITY;
#pragma unroll
    for (int off = 32; off >= 1; off >>= 1) mv = fmaxf(mv, __shfl_xor(mv, off, 64));
    float es = valid ? (expf(vx - mv) + expf(vy - mv)) : 0.f;
#pragma unroll
    for (int off = 32; off >= 1; off >>= 1) es += __shfl_xor(es, off, 64);
    if (valid) {
        float ls = logf(es);
        float2 o; o.x = vx - mv - ls; o.y = vy - mv - ls;
        *(float2*)(out + (size_t)n * DO + 2 * l) = o;
    }
}

extern "C" void kernel_launch(void* const* d_in, const int* in_sizes, int n_in,
                              void* d_out, int out_size, void* d_ws, size_t ws_size,
                              hipStream_t stream) {
    const float* x   = (const float*)d_in[0];
    const int*  ei   = (const int*)d_in[1];
    const float* W1l = (const float*)d_in[2];
    const float* b1  = (const float*)d_in[3];
    const float* W1r = (const float*)d_in[4];
    const float* W2l = (const float*)d_in[5];
    const float* b2  = (const float*)d_in[6];
    const float* W2r = (const float*)d_in[7];
    float* out = (float*)d_out;

    const int E = in_sizes[1] / 2;
    const int N = NN;
    const int* src = ei;
    const int* dst = ei + E;
    const int nbe = (E + EPB - 1) / EPB;

    size_t off = 0;
    auto alloc = [&](size_t nf) { size_t o = off; off += (nf + 63) & ~(size_t)63; return o; };
    size_t o_bcnt   = alloc(NBUCK);        // int, zeroed
    size_t zero_floats = off;
    size_t o_bbase  = alloc(NBUCK + 1);    // int
    size_t o_bcur   = alloc(NBUCK);        // int
    size_t o_eb     = alloc(E);            // int
    size_t o_rowptr = alloc(N);            // int
    size_t o_cnt    = alloc(N);            // int
    size_t o_col    = alloc(E);            // int
    size_t o_inv    = alloc(N);            // float
    size_t o_xb     = alloc((size_t)N * 32);   // u32 (bf16x2)
    size_t o_xa     = alloc((size_t)N * 64);   // u32 (bf16x2): [mean|self] 128 bf16
    size_t o_h      = alloc((size_t)N * 64);   // 128 bf16/row as u32 space
    size_t o_p2lp   = alloc((size_t)N * 32);   // 64 bf16/row
    size_t o_selfp  = alloc((size_t)N * DO);   // f32
    size_t o_wb1    = alloc(16384 / 2);        // 16384 ushort
    size_t o_wb2    = alloc(10240 / 2);        // 10240 ushort
    (void)ws_size;

    float* ws = (float*)d_ws;
    int*   bcnt   = (int*)(ws + o_bcnt);
    int*   bbase  = (int*)(ws + o_bbase);
    int*   bcur   = (int*)(ws + o_bcur);
    int*   eb     = (int*)(ws + o_eb);
    int*   rowptr = (int*)(ws + o_rowptr);
    int*   cnt    = (int*)(ws + o_cnt);
    int*   col    = (int*)(ws + o_col);
    float* inv    = ws + o_inv;
    unsigned* xb  = (unsigned*)(ws + o_xb);
    unsigned* xa  = (unsigned*)(ws + o_xa);
    unsigned short* h    = (unsigned short*)(ws + o_h);
    unsigned* p2lp = (unsigned*)(ws + o_p2lp);
    float* selfp  = ws + o_selfp;
    unsigned short* WB1 = (unsigned short*)(ws + o_wb1);
    unsigned short* WB2 = (unsigned short*)(ws + o_wb2);

    hipMemsetAsync(d_ws, 0, zero_floats * sizeof(float), stream);

    prep_weights_kernel<<<(16384 + 10240 + 255) / 256, 256, 0, stream>>>(
        W1l, W1r, W2l, W2r, WB1, WB2);
    xconv_kernel<<<(N * 32 + 255) / 256, 256, 0, stream>>>(x, xb, N);

    bucket_count_kernel<<<nbe, 256, 0, stream>>>(dst, bcnt, E);
    bucket_scan_kernel<<<1, NBUCK, 0, stream>>>(bcnt, bbase, bcur, E);
    bucket_scatter_kernel<<<nbe, 256, 0, stream>>>(src, dst, bcur, eb, E);
    bucket_fill_kernel<<<NBUCK, 256, 0, stream>>>(eb, bbase, rowptr, cnt, inv, col, N);

    agg1_kernel<<<(N + 3) / 4, 256, 0, stream>>>(xb, rowptr, cnt, inv, col, xa, N);
    gemm1_kernel<<<(N + 63) / 64, 256, 0, stream>>>((const unsigned short*)xa, WB1, b1, h, N);
    gemm2_kernel<<<(N + 63) / 64, 256, 0, stream>>>(h, WB2, b2, (unsigned short*)p2lp, selfp, N);
    agg2_softmax_kernel<<<(N + 3) / 4, 256, 0, stream>>>(p2lp, selfp, rowptr, cnt, inv, col, out, N);
}

// Round 6
// 308.211 us; speedup vs baseline: 4.6694x; 1.0383x over previous
//
#include <hip/hip_runtime.h>
#include <math.h>

#define NN 100000
#define DI 64
#define DH 128
#define DO 40

#define NBUCK 512
#define NPB 196          // nodes per bucket: 512*196 = 100352 >= 100000
#define EPB 4096         // edges per block in bucket count/scatter

typedef __attribute__((ext_vector_type(8))) short bf16x8;
typedef __attribute__((ext_vector_type(4))) float f32x4;

__device__ __forceinline__ unsigned short bf16r(float a) {
    unsigned u = __float_as_uint(a);
    u = (u + 0x7FFF + ((u >> 16) & 1)) >> 16;
    return (unsigned short)u;
}
__device__ __forceinline__ unsigned bf16pair(float a, float b) {
    return (unsigned)bf16r(a) | ((unsigned)bf16r(b) << 16);
}
__device__ __forceinline__ float bflo(unsigned u) { return __uint_as_float(u << 16); }
__device__ __forceinline__ float bfhi(unsigned u) { return __uint_as_float(u & 0xFFFF0000u); }

// ---------- bucketed CSR build ----------

__global__ __launch_bounds__(256) void bucket_count_kernel(const int* __restrict__ dst,
                                                           int* __restrict__ bcnt, int E) {
    __shared__ int h[NBUCK];
    int t = threadIdx.x;
    for (int i = t; i < NBUCK; i += 256) h[i] = 0;
    __syncthreads();
    int base = blockIdx.x * EPB;
    int end = base + EPB; if (end > E) end = E;
    for (int i = base + t; i < end; i += 256)
        atomicAdd(&h[(unsigned)dst[i] / NPB], 1);
    __syncthreads();
    for (int i = t; i < NBUCK; i += 256) {
        int v = h[i];
        if (v) atomicAdd(&bcnt[i], v);
    }
}

__global__ __launch_bounds__(512) void bucket_scan_kernel(const int* __restrict__ bcnt,
                                                          int* __restrict__ bbase,
                                                          int* __restrict__ bcur, int E) {
    __shared__ int s[NBUCK];
    int t = threadIdx.x;
    int v = bcnt[t];
    s[t] = v;
    __syncthreads();
    for (int off = 1; off < NBUCK; off <<= 1) {
        int tmp = (t >= off) ? s[t - off] : 0;
        __syncthreads();
        s[t] += tmp;
        __syncthreads();
    }
    int excl = s[t] - v;
    bbase[t] = excl;
    bcur[t] = excl;
    if (t == 0) bbase[NBUCK] = E;
}

__global__ __launch_bounds__(256) void bucket_scatter_kernel(const int* __restrict__ src,
                                                             const int* __restrict__ dst,
                                                             int* __restrict__ bcur,
                                                             int* __restrict__ eb, int E) {
    __shared__ int h[NBUCK];
    int t = threadIdx.x;
    for (int i = t; i < NBUCK; i += 256) h[i] = 0;
    __syncthreads();
    int base = blockIdx.x * EPB;
    int end = base + EPB; if (end > E) end = E;
    for (int i = base + t; i < end; i += 256)
        atomicAdd(&h[(unsigned)dst[i] / NPB], 1);
    __syncthreads();
    for (int i = t; i < NBUCK; i += 256) {
        int v = h[i];
        h[i] = v ? atomicAdd(&bcur[i], v) : 0;
    }
    __syncthreads();
    for (int i = base + t; i < end; i += 256) {
        int d = dst[i];
        unsigned bk = (unsigned)d / NPB;
        int local = d - (int)bk * NPB;
        int pos = atomicAdd(&h[bk], 1);
        eb[pos] = (local << 17) | src[i];
    }
}

__global__ __launch_bounds__(256) void bucket_fill_kernel(const int* __restrict__ eb,
                                                          const int* __restrict__ bbase,
                                                          int* __restrict__ rowptr,
                                                          int* __restrict__ cntg,
                                                          float* __restrict__ inv,
                                                          int* __restrict__ col, int N) {
    __shared__ int scnt[256];
    __shared__ int scur[256];
    int b = blockIdx.x, t = threadIdx.x;
    int ebeg = bbase[b], eend = bbase[b + 1];
    int nb0 = b * NPB;
    scnt[t] = 0;
    __syncthreads();
    for (int i = ebeg + t; i < eend; i += 256)
        atomicAdd(&scnt[eb[i] >> 17], 1);
    __syncthreads();
    int myc = scnt[t];
    for (int off = 1; off < 256; off <<= 1) {
        int tmp = (t >= off) ? scnt[t - off] : 0;
        __syncthreads();
        scnt[t] += tmp;
        __syncthreads();
    }
    int excl = scnt[t] - myc;
    int node = nb0 + t;
    if (t < NPB && node < N) {
        rowptr[node] = ebeg + excl;
        cntg[node] = myc;
        inv[node] = 1.0f / (float)(myc > 0 ? myc : 1);
    }
    scur[t] = ebeg + excl;
    __syncthreads();
    for (int i = ebeg + t; i < eend; i += 256) {
        int pk = eb[i];
        int l = pk >> 17, s = pk & 0x1FFFF;
        int pos = atomicAdd(&scur[l], 1);
        col[pos] = s;
    }
}

// ---------- weight prep (unchanged layouts) ----------
__global__ __launch_bounds__(256) void prep_weights_kernel(
        const float* __restrict__ W1l, const float* __restrict__ W1r,
        const float* __restrict__ W2l, const float* __restrict__ W2r,
        unsigned short* __restrict__ WB1, unsigned short* __restrict__ WB2) {
    int idx = blockIdx.x * 256 + threadIdx.x;
    if (idx < 16384) {
        int j = idx & 7, lane = (idx >> 3) & 63, ks = (idx >> 9) & 3, nt = idx >> 11;
        int k = ks * 32 + (lane >> 4) * 8 + j;
        int n = nt * 16 + (lane & 15);
        float v = (k < DI) ? W1l[n * DI + k] : W1r[n * DI + (k - DI)];
        WB1[idx] = bf16r(v);
    }
    int idx2 = idx - 16384;
    if (idx2 >= 0 && idx2 < 10240) {
        int j = idx2 & 7, lane = (idx2 >> 3) & 63, ks = (idx2 >> 9) & 3, nt = idx2 >> 11;
        int k = ks * 32 + (lane >> 4) * 8 + j;
        int n = nt * 16 + (lane & 15);
        float v = (n < DO) ? W2l[n * DH + k] : W2r[(n - DO) * DH + k];
        WB2[idx2] = bf16r(v);
    }
}

__global__ void xconv_kernel(const float* __restrict__ x, unsigned* __restrict__ xb, int N) {
    int idx = blockIdx.x * 256 + threadIdx.x;
    if (idx < N * 32) {
        float2 f = ((const float2*)x)[idx];
        xb[idx] = bf16pair(f.x, f.y);
    }
}

// ---------- agg1: wave/node, 8 edges/iter, 16B per lane ----------
__global__ void agg1_kernel(const unsigned* __restrict__ xb, const int* __restrict__ rowptr,
                            const int* __restrict__ cnt, const float* __restrict__ inv,
                            const int* __restrict__ col, unsigned* __restrict__ xa, int N) {
    int n = (blockIdx.x * 256 + threadIdx.x) >> 6;
    int lane = threadIdx.x & 63;
    if (n >= N) return;
    int eslot = lane >> 3, chunk = lane & 7;
    int beg = rowptr[n], deg = cnt[n];
    float a[8];
#pragma unroll
    for (int j = 0; j < 8; j++) a[j] = 0.f;
    for (int i = 0; i < deg; i += 8) {
        int e = i + eslot;
        if (e < deg) {
            int s = col[beg + e];
            uint4 u = *(const uint4*)(xb + (size_t)s * 32 + chunk * 4);
            a[0] += bflo(u.x); a[1] += bfhi(u.x);
            a[2] += bflo(u.y); a[3] += bfhi(u.y);
            a[4] += bflo(u.z); a[5] += bfhi(u.z);
            a[6] += bflo(u.w); a[7] += bfhi(u.w);
        }
    }
#pragma unroll
    for (int off = 8; off <= 32; off <<= 1) {
#pragma unroll
        for (int j = 0; j < 8; j++) a[j] += __shfl_xor(a[j], off, 64);
    }
    float invn = inv[n];
    if (eslot == 0) {
        uint4 o;
        o.x = bf16pair(a[0] * invn, a[1] * invn);
        o.y = bf16pair(a[2] * invn, a[3] * invn);
        o.z = bf16pair(a[4] * invn, a[5] * invn);
        o.w = bf16pair(a[6] * invn, a[7] * invn);
        *(uint4*)(xa + (size_t)n * 64 + chunk * 4) = o;
    } else if (eslot == 1) {
        uint4 u = *(const uint4*)(xb + (size_t)n * 32 + chunk * 4);
        *(uint4*)(xa + (size_t)n * 64 + 32 + chunk * 4) = u;
    }
}

// ---------- GEMM1: h = relu(xa @ Wcat1 + b1) ----------
__global__ __launch_bounds__(256) void gemm1_kernel(const unsigned short* __restrict__ xa,
                                                    const unsigned short* __restrict__ WB1,
                                                    const float* __restrict__ b1,
                                                    unsigned short* __restrict__ h, int N) {
    int w = threadIdx.x >> 6, lane = threadIdx.x & 63;
    int quad = lane >> 4, m = lane & 15;
    int rbase = blockIdx.x * 64 + w * 16;
    int arow = rbase + m; if (arow >= N) arow = N - 1;

    f32x4 acc[8];
#pragma unroll
    for (int nt = 0; nt < 8; nt++) acc[nt] = (f32x4)(0.f);

#pragma unroll
    for (int ks = 0; ks < 4; ks++) {
        bf16x8 a = *(const bf16x8*)(xa + (size_t)arow * 128 + ks * 32 + quad * 8);
#pragma unroll
        for (int nt = 0; nt < 8; nt++) {
            bf16x8 b = *(const bf16x8*)(WB1 + ((size_t)(nt * 4 + ks) * 64 + lane) * 8);
            acc[nt] = __builtin_amdgcn_mfma_f32_16x16x32_bf16(a, b, acc[nt], 0, 0, 0);
        }
    }
#pragma unroll
    for (int nt = 0; nt < 8; nt++) {
        int colj = nt * 16 + m;
        float bj = b1[colj];
#pragma unroll
        for (int r = 0; r < 4; r++) {
            int row = rbase + quad * 4 + r;
            if (row < N) {
                float v = acc[nt][r] + bj;
                h[(size_t)row * 128 + colj] = bf16r(fmaxf(v, 0.f));
            }
        }
    }
}

// ---------- GEMM2: [p2l(40 bf16) | selfp(40 f32)] = h @ Wcat2 ----------
__global__ __launch_bounds__(256) void gemm2_kernel(const unsigned short* __restrict__ h,
                                                    const unsigned short* __restrict__ WB2,
                                                    const float* __restrict__ b2,
                                                    unsigned short* __restrict__ p2,
                                                    float* __restrict__ selfp, int N) {
    int w = threadIdx.x >> 6, lane = threadIdx.x & 63;
    int quad = lane >> 4, m = lane & 15;
    int rbase = blockIdx.x * 64 + w * 16;
    int arow = rbase + m; if (arow >= N) arow = N - 1;

    f32x4 acc[5];
#pragma unroll
    for (int nt = 0; nt < 5; nt++) acc[nt] = (f32x4)(0.f);

#pragma unroll
    for (int ks = 0; ks < 4; ks++) {
        bf16x8 a = *(const bf16x8*)(h + (size_t)arow * 128 + ks * 32 + quad * 8);
#pragma unroll
        for (int nt = 0; nt < 5; nt++) {
            bf16x8 b = *(const bf16x8*)(WB2 + ((size_t)(nt * 4 + ks) * 64 + lane) * 8);
            acc[nt] = __builtin_amdgcn_mfma_f32_16x16x32_bf16(a, b, acc[nt], 0, 0, 0);
        }
    }
#pragma unroll
    for (int nt = 0; nt < 5; nt++) {
        int colj = nt * 16 + m;
#pragma unroll
        for (int r = 0; r < 4; r++) {
            int row = rbase + quad * 4 + r;
            if (row < N) {
                float v = acc[nt][r];
                if (colj < DO) {
                    p2[(size_t)row * 40 + colj] = bf16r(v);
                } else {
                    selfp[(size_t)row * DO + (colj - DO)] = v + b2[colj - DO];
                }
            }
        }
    }
}

// ---------- agg2 + log_softmax: wave/node, 8 edges/iter, 80B rows ----------
__global__ void agg2_softmax_kernel(const unsigned* __restrict__ p2,
                                    const float* __restrict__ selfp,
                                    const int* __restrict__ rowptr,
                                    const int* __restrict__ cnt,
                                    const float* __restrict__ inv,
                                    const int* __restrict__ col,
                                    float* __restrict__ out, int N) {
    int n = (blockIdx.x * 256 + threadIdx.x) >> 6;
    int lane = threadIdx.x & 63;
    if (n >= N) return;
    int eslot = lane >> 3, chunk = lane & 7;
    int beg = rowptr[n], deg = cnt[n];
    float a[8];
#pragma unroll
    for (int j = 0; j < 8; j++) a[j] = 0.f;
    for (int i = 0; i < deg; i += 8) {
        int e = i + eslot;
        if (e < deg && chunk < 5) {
            int s = col[beg + e];
            uint4 u = *(const uint4*)(p2 + (size_t)s * 20 + chunk * 4);
            a[0] += bflo(u.x); a[1] += bfhi(u.x);
            a[2] += bflo(u.y); a[3] += bfhi(u.y);
            a[4] += bflo(u.z); a[5] += bfhi(u.z);
            a[6] += bflo(u.w); a[7] += bfhi(u.w);
        }
    }
#pragma unroll
    for (int off = 8; off <= 32; off <<= 1) {
#pragma unroll
        for (int j = 0; j < 8; j++) a[j] += __shfl_xor(a[j], off, 64);
    }
    float invn = inv[n];
    float v[8];
    bool vc = (chunk < 5);
    if (vc) {
        float4 s0 = *(const float4*)(selfp + (size_t)n * DO + chunk * 8);
        float4 s1 = *(const float4*)(selfp + (size_t)n * DO + chunk * 8 + 4);
        v[0] = a[0] * invn + s0.x; v[1] = a[1] * invn + s0.y;
        v[2] = a[2] * invn + s0.z; v[3] = a[3] * invn + s0.w;
        v[4] = a[4] * invn + s1.x; v[5] = a[5] * invn + s1.y;
        v[6] = a[6] * invn + s1.z; v[7] = a[7] * invn + s1.w;
    } else {
#pragma unroll
        for (int j = 0; j < 8; j++) v[j] = 0.f;
    }
    float mv = -INFINITY;
    if (vc) {
#pragma unroll
        for (int j = 0; j < 8; j++) mv = fmaxf(mv, v[j]);
    }
#pragma unroll
    for (int off = 1; off <= 4; off <<= 1) mv = fmaxf(mv, __shfl_xor(mv, off, 64));
    float es = 0.f;
    if (vc) {
#pragma unroll
        for (int j = 0; j < 8; j++) es += expf(v[j] - mv);
    }
#pragma unroll
    for (int off = 1; off <= 4; off <<= 1) es += __shfl_xor(es, off, 64);
    if (eslot == 0 && vc) {
        float ls = mv + logf(es);
        float4 o0, o1;
        o0.x = v[0] - ls; o0.y = v[1] - ls; o0.z = v[2] - ls; o0.w = v[3] - ls;
        o1.x = v[4] - ls; o1.y = v[5] - ls; o1.z = v[6] - ls; o1.w = v[7] - ls;
        *(float4*)(out + (size_t)n * DO + chunk * 8) = o0;
        *(float4*)(out + (size_t)n * DO + chunk * 8 + 4) = o1;
    }
}

extern "C" void kernel_launch(void* const* d_in, const int* in_sizes, int n_in,
                              void* d_out, int out_size, void* d_ws, size_t ws_size,
                              hipStream_t stream) {
    const float* x   = (const float*)d_in[0];
    const int*  ei   = (const int*)d_in[1];
    const float* W1l = (const float*)d_in[2];
    const float* b1  = (const float*)d_in[3];
    const float* W1r = (const float*)d_in[4];
    const float* W2l = (const float*)d_in[5];
    const float* b2  = (const float*)d_in[6];
    const float* W2r = (const float*)d_in[7];
    float* out = (float*)d_out;

    const int E = in_sizes[1] / 2;
    const int N = NN;
    const int* src = ei;
    const int* dst = ei + E;
    const int nbe = (E + EPB - 1) / EPB;

    size_t off = 0;
    auto alloc = [&](size_t nf) { size_t o = off; off += (nf + 63) & ~(size_t)63; return o; };
    size_t o_bcnt   = alloc(NBUCK);        // int, zeroed
    size_t zero_floats = off;
    size_t o_bbase  = alloc(NBUCK + 1);    // int
    size_t o_bcur   = alloc(NBUCK);        // int
    size_t o_eb     = alloc(E);            // int
    size_t o_rowptr = alloc(N);            // int
    size_t o_cnt    = alloc(N);            // int
    size_t o_col    = alloc(E);            // int
    size_t o_inv    = alloc(N);            // float
    size_t o_xb     = alloc((size_t)N * 32);   // u32 (bf16x2)
    size_t o_xa     = alloc((size_t)N * 64);   // u32: [mean|self] 128 bf16
    size_t o_h      = alloc((size_t)N * 64);   // 128 bf16/row
    size_t o_p2     = alloc((size_t)N * 20);   // 40 bf16/row (80B)
    size_t o_selfp  = alloc((size_t)N * DO);   // f32
    size_t o_wb1    = alloc(16384 / 2);
    size_t o_wb2    = alloc(10240 / 2);
    (void)ws_size;

    float* ws = (float*)d_ws;
    int*   bcnt   = (int*)(ws + o_bcnt);
    int*   bbase  = (int*)(ws + o_bbase);
    int*   bcur   = (int*)(ws + o_bcur);
    int*   eb     = (int*)(ws + o_eb);
    int*   rowptr = (int*)(ws + o_rowptr);
    int*   cnt    = (int*)(ws + o_cnt);
    int*   col    = (int*)(ws + o_col);
    float* inv    = ws + o_inv;
    unsigned* xb  = (unsigned*)(ws + o_xb);
    unsigned* xa  = (unsigned*)(ws + o_xa);
    unsigned short* h    = (unsigned short*)(ws + o_h);
    unsigned* p2  = (unsigned*)(ws + o_p2);
    float* selfp  = ws + o_selfp;
    unsigned short* WB1 = (unsigned short*)(ws + o_wb1);
    unsigned short* WB2 = (unsigned short*)(ws + o_wb2);

    hipMemsetAsync(d_ws, 0, zero_floats * sizeof(float), stream);

    prep_weights_kernel<<<(16384 + 10240 + 255) / 256, 256, 0, stream>>>(
        W1l, W1r, W2l, W2r, WB1, WB2);
    xconv_kernel<<<(N * 32 + 255) / 256, 256, 0, stream>>>(x, xb, N);

    bucket_count_kernel<<<nbe, 256, 0, stream>>>(dst, bcnt, E);
    bucket_scan_kernel<<<1, NBUCK, 0, stream>>>(bcnt, bbase, bcur, E);
    bucket_scatter_kernel<<<nbe, 256, 0, stream>>>(src, dst, bcur, eb, E);
    bucket_fill_kernel<<<NBUCK, 256, 0, stream>>>(eb, bbase, rowptr, cnt, inv, col, N);

    agg1_kernel<<<(N + 3) / 4, 256, 0, stream>>>(xb, rowptr, cnt, inv, col, xa, N);
    gemm1_kernel<<<(N + 63) / 64, 256, 0, stream>>>((const unsigned short*)xa, WB1, b1, h, N);
    gemm2_kernel<<<(N + 63) / 64, 256, 0, stream>>>(h, WB2, b2, (unsigned short*)p2, selfp, N);
    agg2_softmax_kernel<<<(N + 3) / 4, 256, 0, stream>>>(p2, selfp, rowptr, cnt, inv, col, out, N);
}